// Round 2
// baseline (618.277 us; speedup 1.0000x reference)
//
#include <hip/hip_runtime.h>

// GHMC loss, fused single-pass (round 2: VALU-bound -> cut slot-loop ops):
//   loss = sum_b L_b / (cnt_b * n_nonempty)   (tot cancels algebraically)
// Cumulative-GE slots: slot s holds {count, loss-sum} of elements with
// g >= edges[s]; per-bin values recovered by differencing in the finalizer.
// Counts go through __ballot + __popcll => s_bcnt1_b64/s_add on the SCALAR
// pipe (parallel with VALU). Sums accumulate as float2 via v_pk_add_f32.

#define NSLOTS 11  // slot 0 (g>=0, unconditional) + edges .1 ... 1.0+1e-6

typedef float vfloat2 __attribute__((ext_vector_type(2)));

__device__ __forceinline__ float bce(float x, float t) {
    // max(x,0) - x*t + log1p(exp(-|x|)); hw v_exp/v_log, ~2ulp -> negligible
    return fmaxf(x, 0.0f) - x * t + __logf(1.0f + __expf(-fabsf(x)));
}

__global__ __launch_bounds__(256) void ghmc_partial(
    const float4* __restrict__ p4, const float4* __restrict__ t4, int n4,
    const float* __restrict__ p1, const float* __restrict__ t1, long long ntot,
    double* __restrict__ g_sum, unsigned int* __restrict__ g_cnt) {

    const float edges[NSLOTS] = {0.0f, 0.1f, 0.2f, 0.3f, 0.4f, 0.5f,
                                 0.6f, 0.7f, 0.8f, 0.9f, 1.0f + 1e-6f};

    vfloat2 spk[NSLOTS];          // packed per-slot loss sums (v_pk_add_f32)
    unsigned cnt[NSLOTS];         // wave-uniform (ballot+popc) -> SGPRs
#pragma unroll
    for (int s = 0; s < NSLOTS; ++s) { spk[s] = (vfloat2){0.0f, 0.0f}; cnt[s] = 0u; }

    const int stride = gridDim.x * blockDim.x;
    int i = blockIdx.x * blockDim.x + threadIdx.x;
    const int iters = n4 / stride;   // exact for this shape (8)

    float4 p, t;
    if (iters > 0) { p = p4[i]; t = t4[i]; }

    for (int it = 0; it < iters; ++it) {
        const int inext = i + stride;
        float4 pn, tn;
        if (it + 1 < iters) { pn = p4[inext]; tn = t4[inext]; }  // prefetch

        const float gx = fabsf(p.x - t.x), gy = fabsf(p.y - t.y);
        const float gz = fabsf(p.z - t.z), gw = fabsf(p.w - t.w);
        const float lx = bce(p.x, t.x), ly = bce(p.y, t.y);
        const float lz = bce(p.z, t.z), lw = bce(p.w, t.w);

        spk[0] += (vfloat2){lx, ly};
        spk[0] += (vfloat2){lz, lw};
#pragma unroll
        for (int s = 1; s < NSLOTS; ++s) {
            const bool mx = gx >= edges[s];
            const bool my = gy >= edges[s];
            const bool mz = gz >= edges[s];
            const bool mw = gw >= edges[s];
            // counts on the scalar pipe (wave totals)
            cnt[s] += (unsigned)__popcll(__ballot(mx)) +
                      (unsigned)__popcll(__ballot(my)) +
                      (unsigned)__popcll(__ballot(mz)) +
                      (unsigned)__popcll(__ballot(mw));
            spk[s] += (vfloat2){mx ? lx : 0.0f, my ? ly : 0.0f};
            spk[s] += (vfloat2){mz ? lz : 0.0f, mw ? lw : 0.0f};
        }
        p = pn; t = tn; i = inext;
    }
    // slot-0 count: every lane processed 4*iters elements -> 256*iters per wave
    cnt[0] = (unsigned)(64 * 4 * iters);

    // vector-remainder tail (never taken for 16384x4096, kept for correctness)
    for (; i < n4; i += stride) {
        float4 pp = p4[i], tt = t4[i];
        const float e[4][2] = {{pp.x, tt.x}, {pp.y, tt.y}, {pp.z, tt.z}, {pp.w, tt.w}};
        cnt[0] += (unsigned)__popcll(__ballot(1)) * 0u;  // keep shape; count below
        for (int q = 0; q < 4; ++q) {
            const float g = fabsf(e[q][0] - e[q][1]);
            const float l = bce(e[q][0], e[q][1]);
            spk[0] += (vfloat2){l, 0.0f};
            cnt[0] += (unsigned)__popcll(__ballot(1));
#pragma unroll
            for (int s = 1; s < NSLOTS; ++s) {
                const bool m = g >= edges[s];
                cnt[s] += (unsigned)__popcll(__ballot(m));
                spk[s] += (vfloat2){m ? l : 0.0f, 0.0f};
            }
        }
    }
    // scalar tail for ntot % 4 (never taken here); lane 0 of wave 0, block 0
    if (blockIdx.x == 0 && threadIdx.x == 0) {
        for (long long j = (long long)n4 * 4; j < ntot; ++j) {
            const float x = p1[j], tt = t1[j];
            const float g = fabsf(x - tt);
            const float l = bce(x, tt);
            spk[0] += (vfloat2){l, 0.0f};
            cnt[0] += 1u;
#pragma unroll
            for (int s = 1; s < NSLOTS; ++s) {
                if (g >= edges[s]) { cnt[s] += 1u; spk[s] += (vfloat2){l, 0.0f}; }
            }
        }
    }

    // collapse packed pair, then 64-lane tree reduction of the 11 sums
    float sum[NSLOTS];
#pragma unroll
    for (int s = 0; s < NSLOTS; ++s) sum[s] = spk[s].x + spk[s].y;
#pragma unroll
    for (int off = 32; off > 0; off >>= 1) {
#pragma unroll
        for (int s = 0; s < NSLOTS; ++s) sum[s] += __shfl_down(sum[s], off, 64);
    }

    __shared__ float s_sum[4][NSLOTS];
    __shared__ unsigned s_cnt[4][NSLOTS];
    const int wave = threadIdx.x >> 6;
    const int lane = threadIdx.x & 63;
    if (lane == 0) {
#pragma unroll
        for (int s = 0; s < NSLOTS; ++s) { s_sum[wave][s] = sum[s]; s_cnt[wave][s] = cnt[s]; }
    }
    __syncthreads();
    if (threadIdx.x < NSLOTS) {
        const int s = threadIdx.x;
        const float fs = s_sum[0][s] + s_sum[1][s] + s_sum[2][s] + s_sum[3][s];
        const unsigned c = s_cnt[0][s] + s_cnt[1][s] + s_cnt[2][s] + s_cnt[3][s];
        atomicAdd(&g_sum[s], (double)fs);
        atomicAdd(&g_cnt[s], c);
    }
}

__global__ void ghmc_final(const double* __restrict__ g_sum,
                           const unsigned int* __restrict__ g_cnt,
                           float* __restrict__ out) {
    if (blockIdx.x == 0 && threadIdx.x == 0) {
        double loss = 0.0;
        int n = 0;
#pragma unroll
        for (int b = 0; b < 10; ++b) {
            const unsigned c = g_cnt[b] - g_cnt[b + 1];
            if (c > 0u) {
                n += 1;
                loss += (g_sum[b] - g_sum[b + 1]) / (double)c;
            }
        }
        loss /= (n > 0) ? (double)n : 1.0;
        out[0] = (float)loss;
    }
}

extern "C" void kernel_launch(void* const* d_in, const int* in_sizes, int n_in,
                              void* d_out, int out_size, void* d_ws, size_t ws_size,
                              hipStream_t stream) {
    const float* pred = (const float*)d_in[0];
    const float* tgt  = (const float*)d_in[1];
    long long ntot = (long long)in_sizes[0];
    int n4 = (int)(ntot / 4);

    double* g_sum = (double*)d_ws;                                   // 11 doubles
    unsigned int* g_cnt = (unsigned int*)((char*)d_ws + NSLOTS * sizeof(double));

    hipMemsetAsync(d_ws, 0, NSLOTS * sizeof(double) + NSLOTS * sizeof(unsigned int),
                   stream);

    const int threads = 256;
    const int blocks = 8192;  // stride 2,097,152 -> exactly 8 float4/thread
    hipLaunchKernelGGL(ghmc_partial, dim3(blocks), dim3(threads), 0, stream,
                       (const float4*)pred, (const float4*)tgt, n4,
                       pred, tgt, ntot, g_sum, g_cnt);
    hipLaunchKernelGGL(ghmc_final, dim3(1), dim3(64), 0, stream,
                       g_sum, g_cnt, (float*)d_out);
}